// Round 8
// baseline (636.080 us; speedup 1.0000x reference)
//
#include <hip/hip_runtime.h>
#include <math.h>

// AlphaSegmenter fused persistent kernel with hand-rolled grid barrier.
// R2-R6: spill fixes, parallel preps, coalesced h layout, inline exp64,
//        live-range reorder (321us over 12 dispatches).
// R7: cooperative launch silently failed (output = stub value) -> coop
//     validation rejected 1024x256@4/CU (or capture-incompatible).
// R8: same fusion, manual two-level barrier (device-scope atomics +
//     __threadfence), 512 blocks x 256 thr, launch_bounds(256,2):
//     VGPR<=256 -> 8 waves/CU -> capacity exactly 512 blocks. Each block
//     handles 2 tiles. No persistent reg state across barriers (h2 in-place
//     over h1 in global; decode rereads ha). Barrier slots zeroed via
//     hipMemsetAsync before launch (replay-safe). f64 math identical to R6.

#define TT 262144
#define NTILE 1024
#define NBLK 512
#define INVT (1.0 / 262144.0)

__device__ __forceinline__ float spf32(float x) {             // softplus f32
  return fmaxf(x, 0.f) + log1pf(expf(-fabsf(x)));
}

// ---- inline f64 exp: Cody-Waite + degree-12 Horner, |x| <= 700 ----
__device__ __forceinline__ double exp64(double x) {
  const double LOG2E  = 1.4426950408889634074;
  const double LN2_HI = 6.93147180369123816490e-01;
  const double LN2_LO = 1.90821492927058770002e-10;
  double kd = rint(x * LOG2E);
  double r  = fma(-kd, LN2_HI, x);
  r = fma(-kd, LN2_LO, r);
  double p = 2.08767569878681e-9;
  p = fma(p, r, 2.505210838544172e-8);
  p = fma(p, r, 2.755731922398589e-7);
  p = fma(p, r, 2.7557319223985893e-6);
  p = fma(p, r, 2.48015873015873e-5);
  p = fma(p, r, 1.984126984126984e-4);
  p = fma(p, r, 1.388888888888889e-3);
  p = fma(p, r, 8.333333333333333e-3);
  p = fma(p, r, 4.1666666666666664e-2);
  p = fma(p, r, 1.6666666666666666e-1);
  p = fma(p, r, 0.5);
  p = fma(p, r, 1.0);
  p = fma(p, r, 1.0);
  int k = (int)kd;
  long long sb = ((long long)(k + 1023)) << 52;
  return p * __longlong_as_double(sb);
}

__device__ __forceinline__ double tanh64(double x) {
  double ax = fmin(fabs(x), 19.0);
  double e = exp64(2.0 * ax);
  double t = 1.0 - 2.0 / (e + 1.0);
  return x >= 0.0 ? t : -t;
}

union ShMem {
  struct { double Wl[80 * 32]; double ws[4 * 32]; } p2;                      // 21.5KB max
  struct { double Wl[32 * 32]; double ws[4 * 32]; } p4;
  struct { double Wl[32 * 17]; double sm[256]; unsigned long long wm[4]; } p6;
  struct { double tmp[256]; double m[96]; } red;
  struct { double sm[256]; } p0;
  struct { int sc[1024]; } p7;
  struct { float W1l[80 * 32]; float W2l[32 * 16]; double sm[256]; int wlast[4]; } p8;
  struct { double s1[256]; double s2[256]; } p9;
};

// two-level grid barrier: 8 arrival stripes -> 1 top counter -> release flag.
// slot layout: bar[slot*16 + 0..7]=stripes, [8]=top, [9]=flag. memset到0 pre-launch.
__device__ __forceinline__ void gbar(unsigned* bar, int slot) {
  __syncthreads();
  if (threadIdx.x == 0) {
    __threadfence();                                   // publish data (agent scope)
    unsigned* b = bar + slot * 16;
    unsigned old = atomicAdd(&b[blockIdx.x & 7], 1u);  // device-scope by default
    if (old == (NBLK / 8) - 1) {
      unsigned t2 = atomicAdd(&b[8], 1u);
      if (t2 == 7)
        __hip_atomic_store(&b[9], 1u, __ATOMIC_RELAXED, __HIP_MEMORY_SCOPE_AGENT);
    }
    while (__hip_atomic_load(&b[9], __ATOMIC_RELAXED, __HIP_MEMORY_SCOPE_AGENT) == 0u)
      __builtin_amdgcn_s_sleep(1);
    __threadfence();                                   // acquire side
  }
  __syncthreads();
}

__global__ __launch_bounds__(256, 2) void mega(
    const float* __restrict__ s, const float* __restrict__ a, const float* __restrict__ u,
    const float* __restrict__ W1, const float* __restrict__ b1,
    const float* __restrict__ W2, const float* __restrict__ b2,
    const float* __restrict__ W3, const float* __restrict__ b3,
    const float* __restrict__ Wp1, const float* __restrict__ bp1,
    const float* __restrict__ Wp2, const float* __restrict__ bp2,
    double* __restrict__ h, double* __restrict__ ps_s, double* __restrict__ ps_a,
    double* __restrict__ ps_h,
    double* __restrict__ c1v, double* __restrict__ c2v, double* __restrict__ c3v,
    double* __restrict__ lp_part, double* __restrict__ rc_part,
    float* __restrict__ g, int* __restrict__ lastf, int* __restrict__ carry,
    float* __restrict__ loss, float* __restrict__ logits,
    float* __restrict__ ha_out, float* __restrict__ hg_out, unsigned* bar)
{
  __shared__ ShMem sh;
  const int tid = threadIdx.x;
  const int bid = blockIdx.x;

  // ---------- P0: per-tile column sums of s[.][64], a[.][16] ----------
#pragma unroll 1
  for (int tt = 0; tt < 2; ++tt) {
    const int tb = bid + tt * NBLK;
    const long base = (long)tb * 256;
    int col = tid & 63, sub = tid >> 6;
    double acc0 = 0.0;
    for (int r = sub * 64; r < sub * 64 + 64; ++r)
      acc0 += (double)s[(base + r) * 64 + col];
    sh.p0.sm[tid] = acc0;
    __syncthreads();
    if (tid < 64)
      ps_s[tb * 64 + tid] = sh.p0.sm[tid] + sh.p0.sm[64 + tid] +
                            sh.p0.sm[128 + tid] + sh.p0.sm[192 + tid];
    __syncthreads();
    int colA = tid & 15, subA = tid >> 4;
    double accA = 0.0;
    for (int r = subA * 16; r < subA * 16 + 16; ++r)
      accA += (double)a[(base + r) * 16 + colA];
    sh.p0.sm[tid] = accA;
    __syncthreads();
    if (tid < 16) {
      double sa = 0.0;
#pragma unroll
      for (int i = 0; i < 16; ++i) sa += sh.p0.sm[i * 16 + tid];
      ps_a[tb * 16 + tid] = sa;
    }
    __syncthreads();
  }
  gbar(bar, 0);

  // ---------- P1 (block 0): c1 = b1 + mean_x @ W1[80:160] ----------
  if (bid == 0) {
    int c = tid & 63, sub = tid >> 6;
    double acc0 = 0.0;
    for (int i = 0; i < 256; ++i) acc0 += ps_s[(sub * 256 + i) * 64 + c];
    sh.red.tmp[tid] = acc0;
    __syncthreads();
    if (tid < 64)
      sh.red.m[tid] = (sh.red.tmp[tid] + sh.red.tmp[64 + tid] +
                       sh.red.tmp[128 + tid] + sh.red.tmp[192 + tid]) * INVT;
    __syncthreads();
    int cA = tid & 15, subA = tid >> 4;
    double accA = 0.0;
    for (int i = 0; i < 64; ++i) accA += ps_a[(subA * 64 + i) * 16 + cA];
    sh.red.tmp[tid] = accA;
    __syncthreads();
    if (tid < 16) {
      double sa = 0.0;
#pragma unroll
      for (int i = 0; i < 16; ++i) sa += sh.red.tmp[i * 16 + tid];
      sh.red.m[64 + tid] = sa * INVT;
    }
    __syncthreads();
    if (tid < 32) {
      double acc = (double)b1[tid];
      for (int j = 0; j < 80; ++j) acc += sh.red.m[j] * (double)W1[(80 + j) * 32 + tid];
      c1v[tid] = acc;
    }
  }
  gbar(bar, 1);

  // ---------- P2: h1 = tanh([s,a]@W1[:80] + c1) -> h (global); colsums ----------
  {
    for (int i = tid; i < 80 * 32; i += 256) sh.p2.Wl[i] = (double)W1[i];
    __syncthreads();
#pragma unroll 1
    for (int tt = 0; tt < 2; ++tt) {
      const int tb = bid + tt * NBLK;
      const long t = (long)tb * 256 + tid;
      double acc[32];
#pragma unroll
      for (int k = 0; k < 32; ++k) acc[k] = c1v[k];
      const float4* s4 = (const float4*)(s + t * 64);
#pragma unroll 2
      for (int q = 0; q < 16; ++q) {
        float4 v = s4[q];
        const double* w = &sh.p2.Wl[(q * 4) * 32];
        double x0 = (double)v.x, x1 = (double)v.y, x2 = (double)v.z, x3 = (double)v.w;
#pragma unroll
        for (int k = 0; k < 32; ++k)
          acc[k] += x0 * w[k] + x1 * w[32 + k] + x2 * w[64 + k] + x3 * w[96 + k];
      }
      const float4* a4 = (const float4*)(a + t * 16);
#pragma unroll 2
      for (int q = 0; q < 4; ++q) {
        float4 v = a4[q];
        const double* w = &sh.p2.Wl[(64 + q * 4) * 32];
        double x0 = (double)v.x, x1 = (double)v.y, x2 = (double)v.z, x3 = (double)v.w;
#pragma unroll
        for (int k = 0; k < 32; ++k)
          acc[k] += x0 * w[k] + x1 * w[32 + k] + x2 * w[64 + k] + x3 * w[96 + k];
      }
      double* o = h + (size_t)tb * 8192 + tid;       // [tile][col][256] coalesced
#pragma unroll
      for (int k = 0; k < 32; ++k) { acc[k] = tanh64(acc[k]); o[k * 256] = acc[k]; }
      int lane = tid & 63, wave = tid >> 6;
#pragma unroll
      for (int k = 0; k < 32; ++k) {
        double v = acc[k];
        v += __shfl_down(v, 32, 64); v += __shfl_down(v, 16, 64);
        v += __shfl_down(v, 8, 64);  v += __shfl_down(v, 4, 64);
        v += __shfl_down(v, 2, 64);  v += __shfl_down(v, 1, 64);
        if (lane == 0) sh.p2.ws[wave * 32 + k] = v;
      }
      __syncthreads();
      if (tid < 32)
        ps_h[tb * 32 + tid] = sh.p2.ws[tid] + sh.p2.ws[32 + tid] +
                              sh.p2.ws[64 + tid] + sh.p2.ws[96 + tid];
      __syncthreads();
    }
  }
  gbar(bar, 2);

  // ---------- P3 (block 0): c2 ----------
  if (bid == 0) {
    int c = tid & 31, sub = tid >> 5;
    double acc0 = 0.0;
    for (int i = 0; i < 128; ++i) acc0 += ps_h[(sub * 128 + i) * 32 + c];
    sh.red.tmp[tid] = acc0;
    __syncthreads();
    if (tid < 32) {
      double sa = 0.0;
#pragma unroll
      for (int i = 0; i < 8; ++i) sa += sh.red.tmp[i * 32 + tid];
      sh.red.m[tid] = sa * INVT;
    }
    __syncthreads();
    if (tid < 32) {
      double acc = (double)b2[tid];
      for (int j = 0; j < 32; ++j) acc += sh.red.m[j] * (double)W2[(32 + j) * 32 + tid];
      c2v[tid] = acc;
    }
  }
  gbar(bar, 3);

  // ---------- P4: h2 = tanh(h1@W2[:32] + c2), in place; colsums ----------
  {
    for (int i = tid; i < 32 * 32; i += 256) sh.p4.Wl[i] = (double)W2[i];
    __syncthreads();
#pragma unroll 1
    for (int tt = 0; tt < 2; ++tt) {
      const int tb = bid + tt * NBLK;
      const double* x = h + (size_t)tb * 8192 + tid;
      double acc[32];
#pragma unroll
      for (int k = 0; k < 32; ++k) acc[k] = c2v[k];
#pragma unroll 4
      for (int j = 0; j < 32; ++j) {
        double xj = x[j * 256];
#pragma unroll
        for (int k = 0; k < 32; ++k) acc[k] += xj * sh.p4.Wl[j * 32 + k];
      }
      double* o = h + (size_t)tb * 8192 + tid;       // same addrs this thread read
#pragma unroll
      for (int k = 0; k < 32; ++k) { acc[k] = tanh64(acc[k]); o[k * 256] = acc[k]; }
      int lane = tid & 63, wave = tid >> 6;
#pragma unroll
      for (int k = 0; k < 32; ++k) {
        double v = acc[k];
        v += __shfl_down(v, 32, 64); v += __shfl_down(v, 16, 64);
        v += __shfl_down(v, 8, 64);  v += __shfl_down(v, 4, 64);
        v += __shfl_down(v, 2, 64);  v += __shfl_down(v, 1, 64);
        if (lane == 0) sh.p4.ws[wave * 32 + k] = v;
      }
      __syncthreads();
      if (tid < 32)
        ps_h[tb * 32 + tid] = sh.p4.ws[tid] + sh.p4.ws[32 + tid] +
                              sh.p4.ws[64 + tid] + sh.p4.ws[96 + tid];
      __syncthreads();
    }
  }
  gbar(bar, 4);

  // ---------- P5 (block 0): c3 ----------
  if (bid == 0) {
    int c = tid & 31, sub = tid >> 5;
    double acc0 = 0.0;
    for (int i = 0; i < 128; ++i) acc0 += ps_h[(sub * 128 + i) * 32 + c];
    sh.red.tmp[tid] = acc0;
    __syncthreads();
    if (tid < 32) {
      double sa = 0.0;
#pragma unroll
      for (int i = 0; i < 8; ++i) sa += sh.red.tmp[i * 32 + tid];
      sh.red.m[tid] = sa * INVT;
    }
    __syncthreads();
    if (tid < 17) {
      double acc = (double)b3[32 + tid];
      for (int j = 0; j < 32; ++j) acc += sh.red.m[j] * (double)W3[(32 + j) * 49 + 32 + tid];
      c3v[tid] = acc;
    }
  }
  gbar(bar, 5);

  // ---------- P6: g, alpha, Bernoulli, ha, lastf, lp partials ----------
  {
    for (int i = tid; i < 32 * 17; i += 256) {
      int j = i / 17, k = i - j * 17;
      sh.p6.Wl[i] = (double)W3[j * 49 + 32 + k];
    }
    __syncthreads();
#pragma unroll 1
    for (int tt = 0; tt < 2; ++tt) {
      const int tb = bid + tt * NBLK;
      const long t = (long)tb * 256 + tid;
      const double* x = h + (size_t)tb * 8192 + tid;
      double acc[17];
#pragma unroll
      for (int k = 0; k < 17; ++k) acc[k] = c3v[k];
#pragma unroll 4
      for (int j = 0; j < 32; ++j) {
        double xj = x[j * 256];
#pragma unroll
        for (int k = 0; k < 17; ++k) acc[k] += xj * sh.p6.Wl[j * 17 + k];
      }
      float4* g4 = (float4*)(g + t * 16);
      float4 o0, o1, o2, o3;
      o0.x = (float)acc[0];  o0.y = (float)acc[1];  o0.z = (float)acc[2];  o0.w = (float)acc[3];
      o1.x = (float)acc[4];  o1.y = (float)acc[5];  o1.z = (float)acc[6];  o1.w = (float)acc[7];
      o2.x = (float)acc[8];  o2.y = (float)acc[9];  o2.z = (float)acc[10]; o2.w = (float)acc[11];
      o3.x = (float)acc[12]; o3.y = (float)acc[13]; o3.z = (float)acc[14]; o3.w = (float)acc[15];
      g4[0] = o0; g4[1] = o1; g4[2] = o2; g4[3] = o3;
      double l = acc[16];
      double lc = fmin(fmax(l, -700.0), 700.0);
      double alpha = 1.0 / (1.0 + exp64(-lc));
      bool fired = ((double)u[t]) < alpha;
      ha_out[t] = fired ? 1.f : 0.f;
      float lf = (float)l;
      sh.p6.sm[tid] = (double)(fired ? -spf32(-lf) : -spf32(lf));
      unsigned long long bm = __ballot(fired ? 1 : 0);
      if ((tid & 63) == 0) sh.p6.wm[tid >> 6] = bm;
      __syncthreads();
      for (int off = 128; off > 0; off >>= 1) {
        if (tid < off) sh.p6.sm[tid] += sh.p6.sm[tid + off];
        __syncthreads();
      }
      if (tid == 0) {
        lp_part[tb] = sh.p6.sm[0];
        int last = -1;
#pragma unroll
        for (int w = 3; w >= 0; --w)
          if (last < 0 && sh.p6.wm[w])
            last = (int)((long)tb * 256 + w * 64 + (63 - __builtin_clzll(sh.p6.wm[w])));
        lastf[tb] = last;
      }
      __syncthreads();
    }
  }
  gbar(bar, 6);

  // ---------- P7 (block 0): exclusive max-scan over lastf[1024] ----------
  if (bid == 0) {
    for (int i = tid; i < 1024; i += 256) sh.p7.sc[i] = lastf[i];
    __syncthreads();
    for (int off = 1; off < 1024; off <<= 1) {
      int i0 = tid, i1 = tid + 256, i2 = tid + 512, i3 = tid + 768;
      int v0 = (i0 >= off && sh.p7.sc[i0 - off] > sh.p7.sc[i0]) ? sh.p7.sc[i0 - off] : sh.p7.sc[i0];
      int v1 = (i1 >= off && sh.p7.sc[i1 - off] > sh.p7.sc[i1]) ? sh.p7.sc[i1 - off] : sh.p7.sc[i1];
      int v2 = (i2 >= off && sh.p7.sc[i2 - off] > sh.p7.sc[i2]) ? sh.p7.sc[i2 - off] : sh.p7.sc[i2];
      int v3 = (i3 >= off && sh.p7.sc[i3 - off] > sh.p7.sc[i3]) ? sh.p7.sc[i3 - off] : sh.p7.sc[i3];
      __syncthreads();
      sh.p7.sc[i0] = v0; sh.p7.sc[i1] = v1; sh.p7.sc[i2] = v2; sh.p7.sc[i3] = v3;
      __syncthreads();
    }
    for (int i = tid; i < 1024; i += 256) carry[i] = (i == 0) ? -1 : sh.p7.sc[i - 1];
  }
  gbar(bar, 7);

  // ---------- P8: hard_g gather + decode MLP + BCE partials ----------
  {
    for (int i = tid; i < 80 * 32; i += 256) sh.p8.W1l[i] = Wp1[i];
    for (int i = tid; i < 32 * 16; i += 256) sh.p8.W2l[i] = Wp2[i];
#pragma unroll 1
    for (int tt = 0; tt < 2; ++tt) {
      const int tb = bid + tt * NBLK;
      const long t = (long)tb * 256 + tid;
      bool fired = ha_out[t] > 0.5f;
      unsigned long long m = __ballot(fired ? 1 : 0);
      int wave = tid >> 6, lane = tid & 63;
      if (lane == 0)
        sh.p8.wlast[wave] = m ? (int)((long)tb * 256 + wave * 64 + (63 - __builtin_clzll(m))) : -1;
      __syncthreads();
      unsigned long long pm = m & (~0ULL >> (63 - lane));
      int idx = pm ? (int)((long)tb * 256 + wave * 64 + (63 - __builtin_clzll(pm))) : -1;
#pragma unroll
      for (int w = 0; w < 4; ++w)
        if (w < wave && sh.p8.wlast[w] > idx) idx = sh.p8.wlast[w];
      int cr = carry[tb];
      if (cr > idx) idx = cr;
      float msk = idx >= 0 ? 1.f : 0.f;
      const float4* g4 = (const float4*)(g + (long)(idx >= 0 ? idx : 0) * 16);
      float4 v0 = g4[0], v1 = g4[1], v2 = g4[2], v3 = g4[3];
      float hg0  = msk * v0.x, hg1  = msk * v0.y, hg2  = msk * v0.z, hg3  = msk * v0.w;
      float hg4  = msk * v1.x, hg5  = msk * v1.y, hg6  = msk * v1.z, hg7  = msk * v1.w;
      float hg8  = msk * v2.x, hg9  = msk * v2.y, hg10 = msk * v2.z, hg11 = msk * v2.w;
      float hg12 = msk * v3.x, hg13 = msk * v3.y, hg14 = msk * v3.z, hg15 = msk * v3.w;
      hg_out[t * 16 + 0]  = hg0;  hg_out[t * 16 + 1]  = hg1;
      hg_out[t * 16 + 2]  = hg2;  hg_out[t * 16 + 3]  = hg3;
      hg_out[t * 16 + 4]  = hg4;  hg_out[t * 16 + 5]  = hg5;
      hg_out[t * 16 + 6]  = hg6;  hg_out[t * 16 + 7]  = hg7;
      hg_out[t * 16 + 8]  = hg8;  hg_out[t * 16 + 9]  = hg9;
      hg_out[t * 16 + 10] = hg10; hg_out[t * 16 + 11] = hg11;
      hg_out[t * 16 + 12] = hg12; hg_out[t * 16 + 13] = hg13;
      hg_out[t * 16 + 14] = hg14; hg_out[t * 16 + 15] = hg15;
      float acc[32];
#pragma unroll
      for (int k = 0; k < 32; ++k) {          // consume hg first (live-range, R6)
        float v = bp1[k];
        v += hg0  * sh.p8.W1l[(64 + 0)  * 32 + k];  v += hg1  * sh.p8.W1l[(64 + 1)  * 32 + k];
        v += hg2  * sh.p8.W1l[(64 + 2)  * 32 + k];  v += hg3  * sh.p8.W1l[(64 + 3)  * 32 + k];
        v += hg4  * sh.p8.W1l[(64 + 4)  * 32 + k];  v += hg5  * sh.p8.W1l[(64 + 5)  * 32 + k];
        v += hg6  * sh.p8.W1l[(64 + 6)  * 32 + k];  v += hg7  * sh.p8.W1l[(64 + 7)  * 32 + k];
        v += hg8  * sh.p8.W1l[(64 + 8)  * 32 + k];  v += hg9  * sh.p8.W1l[(64 + 9)  * 32 + k];
        v += hg10 * sh.p8.W1l[(64 + 10) * 32 + k];  v += hg11 * sh.p8.W1l[(64 + 11) * 32 + k];
        v += hg12 * sh.p8.W1l[(64 + 12) * 32 + k];  v += hg13 * sh.p8.W1l[(64 + 13) * 32 + k];
        v += hg14 * sh.p8.W1l[(64 + 14) * 32 + k];  v += hg15 * sh.p8.W1l[(64 + 15) * 32 + k];
        acc[k] = v;
      }
      const float4* s4 = (const float4*)(s + t * 64);
#pragma unroll 4
      for (int q = 0; q < 16; ++q) {
        float4 v = s4[q];
        const float* w = &sh.p8.W1l[(q * 4) * 32];
#pragma unroll
        for (int k = 0; k < 32; ++k)
          acc[k] += v.x * w[k] + v.y * w[32 + k] + v.z * w[64 + k] + v.w * w[96 + k];
      }
#pragma unroll
      for (int k = 0; k < 32; ++k) acc[k] = tanhf(acc[k]);
      float lg[16];
#pragma unroll
      for (int k = 0; k < 16; ++k) lg[k] = bp2[k];
#pragma unroll
      for (int j = 0; j < 32; ++j) {
        float hj = acc[j];
        const float* w = &sh.p8.W2l[j * 16];
#pragma unroll
        for (int k = 0; k < 16; ++k) lg[k] += hj * w[k];
      }
#pragma unroll
      for (int k = 0; k < 16; ++k) logits[t * 16 + k] = lg[k];
      const float4* a4 = (const float4*)(a + t * 16);
      double rs = 0.0;
#pragma unroll
      for (int q = 0; q < 4; ++q) {
        float4 av = a4[q];
        float l0 = lg[q * 4], l1 = lg[q * 4 + 1], l2 = lg[q * 4 + 2], l3 = lg[q * 4 + 3];
        rs += (double)(av.x * spf32(-l0) + (1.f - av.x) * spf32(l0));
        rs += (double)(av.y * spf32(-l1) + (1.f - av.y) * spf32(l1));
        rs += (double)(av.z * spf32(-l2) + (1.f - av.z) * spf32(l2));
        rs += (double)(av.w * spf32(-l3) + (1.f - av.w) * spf32(l3));
      }
      sh.p8.sm[tid] = rs;
      __syncthreads();
      for (int off = 128; off > 0; off >>= 1) {
        if (tid < off) sh.p8.sm[tid] += sh.p8.sm[tid + off];
        __syncthreads();
      }
      if (tid == 0) rc_part[tb] = sh.p8.sm[0];
      __syncthreads();
    }
  }
  gbar(bar, 8);

  // ---------- P9 (block 0): loss ----------
  if (bid == 0) {
    double a1 = 0.0, a2 = 0.0;
    for (int i = tid; i < 1024; i += 256) { a1 += lp_part[i]; a2 += rc_part[i]; }
    sh.p9.s1[tid] = a1; sh.p9.s2[tid] = a2;
    __syncthreads();
    for (int off = 128; off > 0; off >>= 1) {
      if (tid < off) { sh.p9.s1[tid] += sh.p9.s1[tid + off]; sh.p9.s2[tid] += sh.p9.s2[tid + off]; }
      __syncthreads();
    }
    if (tid == 0) {
      double R = sh.p9.s1[0] * INVT;
      double M = sh.p9.s2[0] * INVT / 16.0;
      loss[0] = (float)(M + R * M);
    }
  }
}

extern "C" void kernel_launch(void* const* d_in, const int* in_sizes, int n_in,
                              void* d_out, int out_size, void* d_ws, size_t ws_size,
                              hipStream_t stream) {
  const float* s   = (const float*)d_in[0];
  const float* a   = (const float*)d_in[1];
  const float* u   = (const float*)d_in[2];
  const float* W1  = (const float*)d_in[3];
  const float* b1  = (const float*)d_in[4];
  const float* W2  = (const float*)d_in[5];
  const float* b2  = (const float*)d_in[6];
  const float* W3  = (const float*)d_in[7];
  const float* b3  = (const float*)d_in[8];
  const float* Wp1 = (const float*)d_in[9];
  const float* bp1 = (const float*)d_in[10];
  const float* Wp2 = (const float*)d_in[11];
  const float* bp2 = (const float*)d_in[12];

  // workspace carve (f64 first for alignment)
  double* h      = (double*)d_ws;                   // TT*32
  double* ps_s   = h + (size_t)TT * 32;             // NTILE*64
  double* ps_a   = ps_s + (size_t)NTILE * 64;       // NTILE*16
  double* ps_h   = ps_a + (size_t)NTILE * 16;       // NTILE*32
  double* c1v    = ps_h + (size_t)NTILE * 32;       // 32
  double* c2v    = c1v + 32;                        // 32
  double* c3v    = c2v + 32;                        // 24 (17 used)
  double* lp     = c3v + 24;                        // NTILE
  double* rc     = lp + NTILE;                      // NTILE
  float*  g      = (float*)(rc + NTILE);            // TT*16
  int*    lastf  = (int*)(g + (size_t)TT * 16);     // NTILE
  int*    carry  = lastf + NTILE;                   // NTILE
  unsigned* bar  = (unsigned*)(carry + NTILE);      // 9 slots * 16 u32

  float* out    = (float*)d_out;
  float* loss   = out;
  float* logits = out + 1;
  float* ha     = out + 1 + (size_t)TT * 16;
  float* hg     = ha + TT;

  hipMemsetAsync((void*)bar, 0, 9 * 16 * sizeof(unsigned), stream);
  mega<<<dim3(NBLK), dim3(256), 0, stream>>>(
      s, a, u, W1, b1, W2, b2, W3, b3, Wp1, bp1, Wp2, bp2,
      h, ps_s, ps_a, ps_h, c1v, c2v, c3v, lp, rc,
      g, lastf, carry, loss, logits, ha, hg, bar);
}

// Round 9
// 320.009 us; speedup vs baseline: 1.9877x; 1.9877x over previous
//
#include <hip/hip_runtime.h>
#include <math.h>

// AlphaSegmenter: GNN encode (f64 path for exact Bernoulli decisions) ->
// Bernoulli threshold -> segmented carry scan -> decode MLP (f32) -> BCE loss.
// Outputs: [loss(1), logits(T*16), hard_alpha(T), hard_g(T*16)] as f32.
// R2-R6: spill fixes, parallel preps, coalesced h layout, inline exp64,
//        live-range reorder -> 321us over 12 dispatches (all passing).
// R7/R8: grid-barrier fusion attempts -> coop launch rejected / spin barriers
//        cost 370us. Reverted.
// R9: occupancy fix: weight staging in LDS as f32 (exact convert at use ->
//     bit-identical math), halving LDS: h1 21.5->11.3KB, h2 9.2->5.1KB,
//     out 5.5->4.3KB. ~2 blocks/CU -> 5+. launch_bounds(256,4) on f64 kernels.

#define TT 262144
#define NBT 1024   // TT/256 tile blocks
#define NBR 512    // reduction blocks for s,a

__device__ __forceinline__ float spf32(float x) {             // softplus f32
  return fmaxf(x, 0.f) + log1pf(expf(-fabsf(x)));
}

// ---- inline f64 exp: Cody-Waite + degree-12 Horner, |x| <= 700 ----
__device__ __forceinline__ double exp64(double x) {
  const double LOG2E  = 1.4426950408889634074;
  const double LN2_HI = 6.93147180369123816490e-01;
  const double LN2_LO = 1.90821492927058770002e-10;
  double kd = rint(x * LOG2E);
  double r  = fma(-kd, LN2_HI, x);
  r = fma(-kd, LN2_LO, r);
  double p = 2.08767569878681e-9;
  p = fma(p, r, 2.505210838544172e-8);
  p = fma(p, r, 2.755731922398589e-7);
  p = fma(p, r, 2.7557319223985893e-6);
  p = fma(p, r, 2.48015873015873e-5);
  p = fma(p, r, 1.984126984126984e-4);
  p = fma(p, r, 1.388888888888889e-3);
  p = fma(p, r, 8.333333333333333e-3);
  p = fma(p, r, 4.1666666666666664e-2);
  p = fma(p, r, 1.6666666666666666e-1);
  p = fma(p, r, 0.5);
  p = fma(p, r, 1.0);
  p = fma(p, r, 1.0);
  int k = (int)kd;
  long long sb = ((long long)(k + 1023)) << 52;   // 2^k
  return p * __longlong_as_double(sb);
}

__device__ __forceinline__ double tanh64(double x) {
  double ax = fmin(fabs(x), 19.0);                // tanh(19) rounds to <1ulp of 1
  double e = exp64(2.0 * ax);
  double t = 1.0 - 2.0 / (e + 1.0);
  return x >= 0.0 ? t : -t;
}

// ---- deterministic column-sum: in [T,C] -> partials [NBR][C] (f64) ----
template <int C>
__global__ __launch_bounds__(256) void reduce_cols(const float* __restrict__ in,
                                                   double* __restrict__ part) {
  const int rpb = 256 / C;
  int col = threadIdx.x & (C - 1);
  int sub = threadIdx.x / C;
  long row0 = (long)blockIdx.x * rpb + sub;
  long stride = (long)NBR * rpb;
  double acc = 0.0;
  for (long r = row0; r < TT; r += stride) acc += (double)in[r * C + col];
  __shared__ double sm[256];
  sm[threadIdx.x] = acc;
  __syncthreads();
  if (threadIdx.x < C) {
    double s = 0.0;
#pragma unroll
    for (int i = 0; i < rpb; ++i) s += sm[i * C + threadIdx.x];  // fixed order
    part[(long)blockIdx.x * C + threadIdx.x] = s;
  }
}

// ---- c1 = b1 + mean_x @ W1[80:160]; parallel tree over [512][64|16] ----
__global__ __launch_bounds__(640) void prep1(const double* __restrict__ ps_s,
                                             const double* __restrict__ ps_a,
                                             const float* __restrict__ W1,
                                             const float* __restrict__ b1,
                                             double invT, double* __restrict__ c1) {
  __shared__ double partial[80][8];
  __shared__ double mx[80];
  int tid = threadIdx.x;
  int col = tid >> 3, sub = tid & 7;   // 80 cols x 8 threads
  double ssum = 0.0;
  if (col < 64) {
#pragma unroll
    for (int i = 0; i < 64; ++i) ssum += ps_s[(sub * 64 + i) * 64 + col];
  } else {
    int c = col - 64;
#pragma unroll
    for (int i = 0; i < 64; ++i) ssum += ps_a[(sub * 64 + i) * 16 + c];
  }
  partial[col][sub] = ssum;
  __syncthreads();
  if (tid < 80) {
    double s = 0.0;
#pragma unroll
    for (int i = 0; i < 8; ++i) s += partial[tid][i];  // fixed order
    mx[tid] = s * invT;
  }
  __syncthreads();
  if (tid < 32) {
    double acc = (double)b1[tid];
    for (int j = 0; j < 80; ++j) acc += mx[j] * (double)W1[(80 + j) * 32 + tid];
    c1[tid] = acc;
  }
}

// ---- c2 = b2 + mean_h1 @ W2[32:64]; parallel tree over [1024][32] ----
__global__ __launch_bounds__(256) void prep2(const double* __restrict__ ps,
                                             const float* __restrict__ W2,
                                             const float* __restrict__ b2,
                                             double invT, double* __restrict__ c2) {
  __shared__ double partial[32][8];
  __shared__ double mh[32];
  int tid = threadIdx.x;
  int col = tid >> 3, sub = tid & 7;   // 32 cols x 8 threads, 128 each
  double ssum = 0.0;
#pragma unroll
  for (int i = 0; i < 128; ++i) ssum += ps[(sub * 128 + i) * 32 + col];
  partial[col][sub] = ssum;
  __syncthreads();
  if (tid < 32) {
    double s = 0.0;
#pragma unroll
    for (int i = 0; i < 8; ++i) s += partial[tid][i];
    mh[tid] = s * invT;
  }
  __syncthreads();
  if (tid < 32) {
    double acc = (double)b2[tid];
    for (int j = 0; j < 32; ++j) acc += mh[j] * (double)W2[(32 + j) * 32 + tid];
    c2[tid] = acc;
  }
}

// ---- c3[k] = b3[32+k] + mean_h2 @ W3[32:64, 32+k], k=0..16 ----
__global__ __launch_bounds__(256) void prep3(const double* __restrict__ ps,
                                             const float* __restrict__ W3,
                                             const float* __restrict__ b3,
                                             double invT, double* __restrict__ c3) {
  __shared__ double partial[32][8];
  __shared__ double mh[32];
  int tid = threadIdx.x;
  int col = tid >> 3, sub = tid & 7;
  double ssum = 0.0;
#pragma unroll
  for (int i = 0; i < 128; ++i) ssum += ps[(sub * 128 + i) * 32 + col];
  partial[col][sub] = ssum;
  __syncthreads();
  if (tid < 32) {
    double s = 0.0;
#pragma unroll
    for (int i = 0; i < 8; ++i) s += partial[tid][i];
    mh[tid] = s * invT;
  }
  __syncthreads();
  if (tid < 17) {
    double acc = (double)b3[32 + tid];
    for (int j = 0; j < 32; ++j) acc += mh[j] * (double)W3[(32 + j) * 49 + 32 + tid];
    c3[tid] = acc;
  }
}

// h layout: element (block b, col k, row r in 0..255) at h[b*8192 + k*256 + r]

// ---- h1 = tanh([s,a] @ W1[:80] + c1), f64; emits per-block col sums ----
// W staged as f32 (exact f32->f64 cvt at use); LDS 11.3KB -> ~5 blocks/CU.
__global__ __launch_bounds__(256, 4) void h1_kernel(const float* __restrict__ s,
                                                    const float* __restrict__ a,
                                                    const float* __restrict__ W1,
                                                    const double* __restrict__ c1,
                                                    double* __restrict__ h,
                                                    double* __restrict__ ps_h) {
  __shared__ float Wl[80 * 32];
  __shared__ double ws[4 * 32];
  for (int i = threadIdx.x; i < 80 * 32; i += 256) Wl[i] = W1[i];
  __syncthreads();
  long t = (long)blockIdx.x * 256 + threadIdx.x;
  double acc[32];
#pragma unroll
  for (int k = 0; k < 32; ++k) acc[k] = c1[k];
  const float4* s4 = (const float4*)(s + t * 64);
#pragma unroll 2
  for (int q = 0; q < 16; ++q) {
    float4 v = s4[q];
    const float* w = &Wl[(q * 4) * 32];
    double x0 = (double)v.x, x1 = (double)v.y, x2 = (double)v.z, x3 = (double)v.w;
#pragma unroll
    for (int k = 0; k < 32; ++k)
      acc[k] += x0 * (double)w[k] + x1 * (double)w[32 + k] +
                x2 * (double)w[64 + k] + x3 * (double)w[96 + k];
  }
  const float4* a4 = (const float4*)(a + t * 16);
#pragma unroll 2
  for (int q = 0; q < 4; ++q) {
    float4 v = a4[q];
    const float* w = &Wl[(64 + q * 4) * 32];
    double x0 = (double)v.x, x1 = (double)v.y, x2 = (double)v.z, x3 = (double)v.w;
#pragma unroll
    for (int k = 0; k < 32; ++k)
      acc[k] += x0 * (double)w[k] + x1 * (double)w[32 + k] +
                x2 * (double)w[64 + k] + x3 * (double)w[96 + k];
  }
  double* o = h + (size_t)blockIdx.x * 8192 + threadIdx.x;
#pragma unroll
  for (int k = 0; k < 32; ++k) { acc[k] = tanh64(acc[k]); o[k * 256] = acc[k]; }
  int lane = threadIdx.x & 63, wave = threadIdx.x >> 6;
#pragma unroll
  for (int k = 0; k < 32; ++k) {
    double v = acc[k];
    v += __shfl_down(v, 32, 64); v += __shfl_down(v, 16, 64);
    v += __shfl_down(v, 8, 64);  v += __shfl_down(v, 4, 64);
    v += __shfl_down(v, 2, 64);  v += __shfl_down(v, 1, 64);
    if (lane == 0) ws[wave * 32 + k] = v;
  }
  __syncthreads();
  if (threadIdx.x < 32) {
    double ssum = ws[threadIdx.x] + ws[32 + threadIdx.x] + ws[64 + threadIdx.x] +
                  ws[96 + threadIdx.x];
    ps_h[blockIdx.x * 32 + threadIdx.x] = ssum;
  }
}

// ---- h2 = tanh(h1 @ W2[:32] + c2), f64, in place; col sums; LDS 5.1KB ----
__global__ __launch_bounds__(256, 4) void h2_kernel(const double* __restrict__ hin,
                                                    const float* __restrict__ W2,
                                                    const double* __restrict__ c2,
                                                    double* __restrict__ hout,
                                                    double* __restrict__ ps_h) {
  __shared__ float Wl[32 * 32];
  __shared__ double ws[4 * 32];
  for (int i = threadIdx.x; i < 32 * 32; i += 256) Wl[i] = W2[i];
  __syncthreads();
  const double* x = hin + (size_t)blockIdx.x * 8192 + threadIdx.x;
  double acc[32];
#pragma unroll
  for (int k = 0; k < 32; ++k) acc[k] = c2[k];
#pragma unroll 4
  for (int j = 0; j < 32; ++j) {
    double xj = x[j * 256];                 // 512B coalesced per wave
#pragma unroll
    for (int k = 0; k < 32; ++k) acc[k] += xj * (double)Wl[j * 32 + k];
  }
  double* o = hout + (size_t)blockIdx.x * 8192 + threadIdx.x;
#pragma unroll
  for (int k = 0; k < 32; ++k) { acc[k] = tanh64(acc[k]); o[k * 256] = acc[k]; }
  int lane = threadIdx.x & 63, wave = threadIdx.x >> 6;
#pragma unroll
  for (int k = 0; k < 32; ++k) {
    double v = acc[k];
    v += __shfl_down(v, 32, 64); v += __shfl_down(v, 16, 64);
    v += __shfl_down(v, 8, 64);  v += __shfl_down(v, 4, 64);
    v += __shfl_down(v, 2, 64);  v += __shfl_down(v, 1, 64);
    if (lane == 0) ws[wave * 32 + k] = v;
  }
  __syncthreads();
  if (threadIdx.x < 32) {
    double ssum = ws[threadIdx.x] + ws[32 + threadIdx.x] + ws[64 + threadIdx.x] +
                  ws[96 + threadIdx.x];
    ps_h[blockIdx.x * 32 + threadIdx.x] = ssum;
  }
}

// ---- g, alpha, hard_alpha, per-block last-fired, logprob partials; LDS 4.3KB ----
__global__ __launch_bounds__(256, 4) void out_kernel(const double* __restrict__ h,
                                                     const float* __restrict__ W3,
                                                     const double* __restrict__ c3,
                                                     const float* __restrict__ u,
                                                     float* __restrict__ g, float* __restrict__ ha,
                                                     int* __restrict__ lastf,
                                                     double* __restrict__ lp_part) {
  __shared__ float Wl[32 * 17];
  __shared__ double sm[256];
  __shared__ unsigned long long wm[4];
  for (int i = threadIdx.x; i < 32 * 17; i += 256) {
    int j = i / 17, k = i - j * 17;
    Wl[i] = W3[j * 49 + 32 + k];
  }
  __syncthreads();
  long t = (long)blockIdx.x * 256 + threadIdx.x;
  const double* x = h + (size_t)blockIdx.x * 8192 + threadIdx.x;
  double acc[17];
#pragma unroll
  for (int k = 0; k < 17; ++k) acc[k] = c3[k];
#pragma unroll 4
  for (int j = 0; j < 32; ++j) {
    double xj = x[j * 256];                 // 512B coalesced per wave
#pragma unroll
    for (int k = 0; k < 17; ++k) acc[k] += xj * (double)Wl[j * 17 + k];
  }
  float4* g4 = (float4*)(g + t * 16);
  float4 o0, o1, o2, o3;
  o0.x = (float)acc[0];  o0.y = (float)acc[1];  o0.z = (float)acc[2];  o0.w = (float)acc[3];
  o1.x = (float)acc[4];  o1.y = (float)acc[5];  o1.z = (float)acc[6];  o1.w = (float)acc[7];
  o2.x = (float)acc[8];  o2.y = (float)acc[9];  o2.z = (float)acc[10]; o2.w = (float)acc[11];
  o3.x = (float)acc[12]; o3.y = (float)acc[13]; o3.z = (float)acc[14]; o3.w = (float)acc[15];
  g4[0] = o0; g4[1] = o1; g4[2] = o2; g4[3] = o3;
  double l = acc[16];
  double lc = fmin(fmax(l, -700.0), 700.0);
  double alpha = 1.0 / (1.0 + exp64(-lc));
  bool fired = ((double)u[t]) < alpha;
  ha[t] = fired ? 1.f : 0.f;
  float lf = (float)l;                      // log-prob only feeds the loss: f32 ok
  sm[threadIdx.x] = (double)(fired ? -spf32(-lf) : -spf32(lf));
  unsigned long long bm = __ballot(fired ? 1 : 0);
  if ((threadIdx.x & 63) == 0) wm[threadIdx.x >> 6] = bm;
  __syncthreads();
  for (int off = 128; off > 0; off >>= 1) {
    if (threadIdx.x < off) sm[threadIdx.x] += sm[threadIdx.x + off];
    __syncthreads();
  }
  if (threadIdx.x == 0) {
    lp_part[blockIdx.x] = sm[0];
    int last = -1;
#pragma unroll
    for (int w = 3; w >= 0; --w) {
      if (last < 0 && wm[w])
        last = (int)((long)blockIdx.x * 256 + w * 64 + (63 - __builtin_clzll(wm[w])));
    }
    lastf[blockIdx.x] = last;
  }
}

// ---- exclusive max-scan over per-block last-fired indices ----
__global__ __launch_bounds__(1024) void carry_scan(const int* __restrict__ lastf,
                                                   int* __restrict__ carry, int n) {
  __shared__ int sm[1024];
  int tid = threadIdx.x;
  sm[tid] = (tid < n) ? lastf[tid] : -1;
  __syncthreads();
  for (int off = 1; off < n; off <<= 1) {
    int v = sm[tid];
    int o = (tid >= off) ? sm[tid - off] : -1;
    __syncthreads();
    sm[tid] = v > o ? v : o;
    __syncthreads();
  }
  if (tid < n) carry[tid] = (tid == 0) ? -1 : sm[tid - 1];
}

// ---- scan-combine, hard_g gather, decode MLP, logits, BCE partials ----
__global__ __launch_bounds__(256, 2) void decode_kernel(
    const float* __restrict__ s, const float* __restrict__ a, const float* __restrict__ g,
    const float* __restrict__ Wp1, const float* __restrict__ bp1, const float* __restrict__ Wp2,
    const float* __restrict__ bp2, const float* __restrict__ ha, const int* __restrict__ carry,
    float* __restrict__ logits, float* __restrict__ hardg, double* __restrict__ rc_part) {
  __shared__ float W1l[80 * 32];
  __shared__ float W2l[32 * 16];
  __shared__ int wlast[4];
  __shared__ double sm[256];
  long t = (long)blockIdx.x * 256 + threadIdx.x;
  bool fired = ha[t] > 0.5f;
  unsigned long long m = __ballot(fired ? 1 : 0);
  int wave = threadIdx.x >> 6, lane = threadIdx.x & 63;
  if (lane == 0)
    wlast[wave] = m ? (int)((long)blockIdx.x * 256 + wave * 64 + (63 - __builtin_clzll(m))) : -1;
  for (int i = threadIdx.x; i < 80 * 32; i += 256) W1l[i] = Wp1[i];
  for (int i = threadIdx.x; i < 32 * 16; i += 256) W2l[i] = Wp2[i];
  __syncthreads();
  unsigned long long pm = m & (~0ULL >> (63 - lane));
  int idx = pm ? (int)((long)blockIdx.x * 256 + wave * 64 + (63 - __builtin_clzll(pm))) : -1;
#pragma unroll
  for (int w = 0; w < 4; ++w)
    if (w < wave && wlast[w] > idx) idx = wlast[w];
  int cr = carry[blockIdx.x];
  if (cr > idx) idx = cr;
  // non-divergent gather: clamp index, mask result
  float msk = idx >= 0 ? 1.f : 0.f;
  const float4* g4 = (const float4*)(g + (long)(idx >= 0 ? idx : 0) * 16);
  float4 v0 = g4[0], v1 = g4[1], v2 = g4[2], v3 = g4[3];
  float hg0  = msk * v0.x, hg1  = msk * v0.y, hg2  = msk * v0.z, hg3  = msk * v0.w;
  float hg4  = msk * v1.x, hg5  = msk * v1.y, hg6  = msk * v1.z, hg7  = msk * v1.w;
  float hg8  = msk * v2.x, hg9  = msk * v2.y, hg10 = msk * v2.z, hg11 = msk * v2.w;
  float hg12 = msk * v3.x, hg13 = msk * v3.y, hg14 = msk * v3.z, hg15 = msk * v3.w;
  // store hard_g now (scalar stores; d_out region is only 4B aligned)
  hardg[t * 16 + 0]  = hg0;  hardg[t * 16 + 1]  = hg1;
  hardg[t * 16 + 2]  = hg2;  hardg[t * 16 + 3]  = hg3;
  hardg[t * 16 + 4]  = hg4;  hardg[t * 16 + 5]  = hg5;
  hardg[t * 16 + 6]  = hg6;  hardg[t * 16 + 7]  = hg7;
  hardg[t * 16 + 8]  = hg8;  hardg[t * 16 + 9]  = hg9;
  hardg[t * 16 + 10] = hg10; hardg[t * 16 + 11] = hg11;
  hardg[t * 16 + 12] = hg12; hardg[t * 16 + 13] = hg13;
  hardg[t * 16 + 14] = hg14; hardg[t * 16 + 15] = hg15;
  float acc[32];
  // consume hg FIRST so its registers die before the big s-loop
  // (FP sum-order differs from reference by ~1e-6 on logits; threshold 6e-2)
#pragma unroll
  for (int k = 0; k < 32; ++k) {
    float v = bp1[k];
    v += hg0  * W1l[(64 + 0)  * 32 + k];  v += hg1  * W1l[(64 + 1)  * 32 + k];
    v += hg2  * W1l[(64 + 2)  * 32 + k];  v += hg3  * W1l[(64 + 3)  * 32 + k];
    v += hg4  * W1l[(64 + 4)  * 32 + k];  v += hg5  * W1l[(64 + 5)  * 32 + k];
    v += hg6  * W1l[(64 + 6)  * 32 + k];  v += hg7  * W1l[(64 + 7)  * 32 + k];
    v += hg8  * W1l[(64 + 8)  * 32 + k];  v += hg9  * W1l[(64 + 9)  * 32 + k];
    v += hg10 * W1l[(64 + 10) * 32 + k];  v += hg11 * W1l[(64 + 11) * 32 + k];
    v += hg12 * W1l[(64 + 12) * 32 + k];  v += hg13 * W1l[(64 + 13) * 32 + k];
    v += hg14 * W1l[(64 + 14) * 32 + k];  v += hg15 * W1l[(64 + 15) * 32 + k];
    acc[k] = v;
  }
  const float4* s4 = (const float4*)(s + t * 64);
#pragma unroll 4
  for (int q = 0; q < 16; ++q) {
    float4 v = s4[q];
    const float* w = &W1l[(q * 4) * 32];
#pragma unroll
    for (int k = 0; k < 32; ++k)
      acc[k] += v.x * w[k] + v.y * w[32 + k] + v.z * w[64 + k] + v.w * w[96 + k];
  }
#pragma unroll
  for (int k = 0; k < 32; ++k) acc[k] = tanhf(acc[k]);
  float lg[16];
#pragma unroll
  for (int k = 0; k < 16; ++k) lg[k] = bp2[k];
#pragma unroll
  for (int j = 0; j < 32; ++j) {
    float hj = acc[j];
    const float* w = &W2l[j * 16];
#pragma unroll
    for (int k = 0; k < 16; ++k) lg[k] += hj * w[k];
  }
#pragma unroll
  for (int k = 0; k < 16; ++k) logits[t * 16 + k] = lg[k];
  const float4* a4 = (const float4*)(a + t * 16);
  double rs = 0.0;
#pragma unroll
  for (int q = 0; q < 4; ++q) {
    float4 av = a4[q];
    float l0 = lg[q * 4], l1 = lg[q * 4 + 1], l2 = lg[q * 4 + 2], l3 = lg[q * 4 + 3];
    rs += (double)(av.x * spf32(-l0) + (1.f - av.x) * spf32(l0));
    rs += (double)(av.y * spf32(-l1) + (1.f - av.y) * spf32(l1));
    rs += (double)(av.z * spf32(-l2) + (1.f - av.z) * spf32(l2));
    rs += (double)(av.w * spf32(-l3) + (1.f - av.w) * spf32(l3));
  }
  sm[threadIdx.x] = rs;
  __syncthreads();
  for (int off = 128; off > 0; off >>= 1) {
    if (threadIdx.x < off) sm[threadIdx.x] += sm[threadIdx.x + off];
    __syncthreads();
  }
  if (threadIdx.x == 0) rc_part[blockIdx.x] = sm[0];
}

// ---- loss = mean(recon) * (1 + mean(log_probs)) ----
__global__ __launch_bounds__(256) void finalize(const double* __restrict__ lp_part,
                                                const double* __restrict__ rc_part, int nb,
                                                double invT, float* __restrict__ out0) {
  __shared__ double s1[256], s2[256];
  int tid = threadIdx.x;
  double a1 = 0, a2 = 0;
  for (int i = tid; i < nb; i += 256) { a1 += lp_part[i]; a2 += rc_part[i]; }
  s1[tid] = a1; s2[tid] = a2;
  __syncthreads();
  for (int off = 128; off > 0; off >>= 1) {
    if (tid < off) { s1[tid] += s1[tid + off]; s2[tid] += s2[tid + off]; }
    __syncthreads();
  }
  if (tid == 0) {
    double R = s1[0] * invT;            // mean log_probs over T
    double M = s2[0] * invT / 16.0;     // mean recon over T*16
    out0[0] = (float)(M + R * M);
  }
}

extern "C" void kernel_launch(void* const* d_in, const int* in_sizes, int n_in,
                              void* d_out, int out_size, void* d_ws, size_t ws_size,
                              hipStream_t stream) {
  const float* s   = (const float*)d_in[0];
  const float* a   = (const float*)d_in[1];
  const float* u   = (const float*)d_in[2];
  const float* W1  = (const float*)d_in[3];
  const float* b1  = (const float*)d_in[4];
  const float* W2  = (const float*)d_in[5];
  const float* b2  = (const float*)d_in[6];
  const float* W3  = (const float*)d_in[7];
  const float* b3  = (const float*)d_in[8];
  const float* Wp1 = (const float*)d_in[9];
  const float* bp1 = (const float*)d_in[10];
  const float* Wp2 = (const float*)d_in[11];
  const float* bp2 = (const float*)d_in[12];

  const double invT = 1.0 / (double)TT;

  // workspace carve (f64 first for alignment)
  double* h      = (double*)d_ws;                 // TT*32 (h1, then h2 in place)
  double* ps_s   = h + (size_t)TT * 32;           // NBR*64
  double* ps_a   = ps_s + (size_t)NBR * 64;       // NBR*16
  double* ps_h   = ps_a + (size_t)NBR * 16;       // NBT*32 (h1 partials, then h2)
  double* c1     = ps_h + (size_t)NBT * 32;       // 32
  double* c2     = c1 + 32;                       // 32
  double* c3     = c2 + 32;                       // 24 (17 used)
  double* lp_part= c3 + 24;                       // NBT
  double* rc_part= lp_part + NBT;                 // NBT
  float*  g      = (float*)(rc_part + NBT);       // TT*16
  int*    lastf  = (int*)(g + (size_t)TT * 16);   // NBT
  int*    carry  = lastf + NBT;                   // NBT

  float* out    = (float*)d_out;
  float* loss   = out;
  float* logits = out + 1;
  float* ha     = out + 1 + (size_t)TT * 16;
  float* hg     = ha + TT;

  reduce_cols<64><<<NBR, 256, 0, stream>>>(s, ps_s);
  reduce_cols<16><<<NBR, 256, 0, stream>>>(a, ps_a);
  prep1<<<1, 640, 0, stream>>>(ps_s, ps_a, W1, b1, invT, c1);
  h1_kernel<<<NBT, 256, 0, stream>>>(s, a, W1, c1, h, ps_h);
  prep2<<<1, 256, 0, stream>>>(ps_h, W2, b2, invT, c2);
  h2_kernel<<<NBT, 256, 0, stream>>>(h, W2, c2, h, ps_h);
  prep3<<<1, 256, 0, stream>>>(ps_h, W3, b3, invT, c3);
  out_kernel<<<NBT, 256, 0, stream>>>(h, W3, c3, u, g, ha, lastf, lp_part);
  carry_scan<<<1, NBT, 0, stream>>>(lastf, carry, NBT);
  decode_kernel<<<NBT, 256, 0, stream>>>(s, a, g, Wp1, bp1, Wp2, bp2, ha, carry,
                                         logits, hg, rc_part);
  finalize<<<1, 256, 0, stream>>>(lp_part, rc_part, NBT, invT, loss);
}